// Round 13
// baseline (3780.033 us; speedup 1.0000x reference)
//
#include <hip/hip_runtime.h>

// LSTM encoder-decoder, MI355X. B=1024, S=256, IN=8, H=512, F=96.
// R13: 2 wgs/CU for latency hiding. R6/R9/R11/R12 all ~2.6-3.1 ms with pipes
// ~85% idle and MFMA-busy invariant (~318 us = the 136-MFMA/SIMD floor at
// ~19.4 cyc each): the ~5 us/step of sync wait cannot be hidden at 1 wg/CU.
// Grid 512 = 32 M-groups (32 rows) x 16 N-wgs; __launch_bounds__(256,2);
// 172 VGPR -> 2 waves/SIMD co-resident: while one wg waits (s_sleep), the
// other computes. Per-SIMD MFMA and per-CU L2 traffic unchanged.
// Data path/primitives = R9 verbatim (proven): fragment-layout hbuf, single
// ld16 ("=&v") sc0 loads, tied vmcnt(0), RMW-poll barrier (poll-load ban),
// weights in VGPRs (bw[2][17]), c-state in regs, folded decoder feedback.
// Mode B fallback (placement not 64 wgs/XCD): agent-scope + sc0 sc1 MALL.

#define Hh 512
#define K2 544
#define BATCH 1024
#define SEQ 256
#define FCAST 96
#define SHS 40                   // sH stride (f16)
#define HBP (32 * 16384)         // hbuf f16 per parity (32 groups x 16384)

typedef _Float16 f16;
typedef _Float16 f16x8 __attribute__((ext_vector_type(8)));
typedef float f32x4 __attribute__((ext_vector_type(4)));

__device__ __forceinline__ float sigf(float v) { return 1.0f / (1.0f + __expf(-v)); }
__device__ __forceinline__ float tanhf_(float v) { return 1.0f - 2.0f / (__expf(2.0f * v) + 1.0f); }

__device__ __forceinline__ f16x8 ld16(const f16* p, bool byp) {
  f16x8 d;
  if (byp) asm volatile("global_load_dwordx4 %0, %1, off sc0 sc1" : "=&v"(d) : "v"(p) : "memory");
  else     asm volatile("global_load_dwordx4 %0, %1, off sc0"     : "=&v"(d) : "v"(p) : "memory");
  return d;
}
__device__ __forceinline__ void st16(f16* p, f16x8 v, bool byp) {
  if (byp) asm volatile("global_store_dwordx4 %0, %1, off sc0 sc1" :: "v"(p), "v"(v) : "memory");
  else     asm volatile("global_store_dwordx4 %0, %1, off"         :: "v"(p), "v"(v) : "memory");
}
__device__ __forceinline__ int atomic_add_l2(int* p, int v) {
  int old;
  asm volatile("global_atomic_add %0, %1, %2, off sc0\n\ts_waitcnt vmcnt(0)"
               : "=v"(old) : "v"(p), "v"(v) : "memory");
  return old;
}
__device__ __forceinline__ void wait_frags4(f16x8 (&fr)[2][2]) {
  asm volatile("s_waitcnt vmcnt(0)"
               : "+v"(fr[0][0]), "+v"(fr[0][1]), "+v"(fr[1][0]), "+v"(fr[1][1]));
}

// ---------------- prep: permute + fp16-convert + fold weights (unchanged) ----
// col n: nslot=n>>7, c=n&127, w=c>>5, cc=c&31, ct=cc>>4, l4=cc&15;
// gate=ct*2+(l4>>3), j=l4&7, unit=nslot*32+w*8+j; row r=gate*512+unit.
// K: [0,512)=Whh, [512,520)=Wih(enc), [520,544)=0.
__global__ void prep_weights(const float* __restrict__ encWih, const float* __restrict__ encWhh,
                             const float* __restrict__ decWih, const float* __restrict__ decWhh,
                             const float* __restrict__ encBih, const float* __restrict__ encBhh,
                             const float* __restrict__ decBih, const float* __restrict__ decBhh,
                             const float* __restrict__ outW, const float* __restrict__ outB,
                             f16* __restrict__ encT, f16* __restrict__ decPW, f16* __restrict__ decFW,
                             float* __restrict__ bE, float* __restrict__ bP, float* __restrict__ bF) {
  int id = blockIdx.x * 256 + threadIdx.x;
  if (id >= 2048 * 68) return;
  int n = id / 68, c8 = id % 68;
  int nslot = n >> 7, c = n & 127, w = c >> 5, cc = c & 31, ct = cc >> 4, l4v = cc & 15;
  int g = ct * 2 + (l4v >> 3), j = l4v & 7;
  int unit = nslot * 32 + w * 8 + j, r = g * Hh + unit;
  size_t o = (size_t)n * K2 + c8 * 8;
  if (c8 < 64) {
    float dwih = decWih[r];
#pragma unroll
    for (int e = 0; e < 8; ++e) {
      int k = c8 * 8 + e;
      encT[o + e] = (f16)encWhh[(size_t)r * Hh + k];
      float dw = decWhh[(size_t)r * Hh + k];
      decPW[o + e] = (f16)dw;
      decFW[o + e] = (f16)(dw + outW[k] * dwih);
    }
  } else if (c8 == 64) {
#pragma unroll
    for (int e = 0; e < 8; ++e) {
      encT[o + e] = (f16)encWih[r * 8 + e];
      decPW[o + e] = (f16)0.f;
      decFW[o + e] = (f16)0.f;
    }
  } else {
#pragma unroll
    for (int e = 0; e < 8; ++e) {
      encT[o + e] = (f16)0.f;
      decPW[o + e] = (f16)0.f;
      decFW[o + e] = (f16)0.f;
    }
  }
  if (c8 == 0) {
    bE[n] = encBih[r] + encBhh[r];
    float bd = decBih[r] + decBhh[r];
    bP[n] = bd;
    bF[n] = bd + outB[0] * decWih[r];
  }
}

__global__ void init_state(f16* __restrict__ hbuf, float* __restrict__ out,
                           const float* __restrict__ outB, int* __restrict__ sync) {
  int i = blockIdx.x * 256 + threadIdx.x;  // 2048 blocks
  unsigned int* hb = (unsigned int*)hbuf;  // 2*HBP f16 = 524288 u32
  if (i < 524288) hb[i] = 0u;
  if (i < BATCH * FCAST) out[i] = outB[0];
  if (i < 8192) sync[i] = 0;
}

// ---------------- persistent kernel: 512 wgs, 2 per CU ----------------
__global__ __launch_bounds__(256, 2) void lstm_persist(
    const f16* __restrict__ encT, const f16* __restrict__ decPW, const f16* __restrict__ decFW,
    const float* __restrict__ bE, const float* __restrict__ bP, const float* __restrict__ bF,
    const float* __restrict__ x, const float* __restrict__ outW,
    f16* __restrict__ hbuf, float* __restrict__ out, int* __restrict__ sync) {
  __shared__ __align__(16) f16 sH[32 * SHS];  // 2560 B
  __shared__ int sInfo[2];

  int* cnt = sync;            // 32 groups, stride 64 ints (256 B apart)
  int* slots = sync + 4096;
  int* arrive = sync + 4104;

  const int T = threadIdx.x;
  const int w = T >> 6, lane = T & 63, l4 = lane & 15, q = lane >> 4;
  const int j = l4 & 7;
  const bool lo = (l4 < 8);

  int xcd;
  asm("s_getreg_b32 %0, hwreg(HW_REG_XCC_ID)" : "=s"(xcd));
  xcd &= 7;

  // ---- one-time self-organization (agent scope, proven) ----
  if (T == 0) {
    int r = __hip_atomic_fetch_add(&slots[xcd], 1, __ATOMIC_RELAXED, __HIP_MEMORY_SCOPE_AGENT);
    sInfo[0] = r;
    __hip_atomic_fetch_add(arrive, 1, __ATOMIC_RELAXED, __HIP_MEMORY_SCOPE_AGENT);
    while (__hip_atomic_load(arrive, __ATOMIC_RELAXED, __HIP_MEMORY_SCOPE_AGENT) < 512)
      __builtin_amdgcn_s_sleep(2);
    int ok = 1;
    for (int xx = 0; xx < 8; ++xx)
      ok &= (__hip_atomic_load(&slots[xx], __ATOMIC_RELAXED, __HIP_MEMORY_SCOPE_AGENT) == 64);
    sInfo[1] = ok;
  }
  __syncthreads();
  const int rank = sInfo[0];
  const bool uni = (sInfo[1] != 0);
  int group, nslot;
  if (uni) { group = xcd * 4 + (rank >> 4); nslot = rank & 15; }  // XCD-local groups
  else     { group = (int)blockIdx.x >> 4;  nslot = (int)blockIdx.x & 15; }
  const int m0 = group * 32, n0 = nslot * 128, u0 = nslot * 32;
  int* myCnt = cnt + group * 64;

  f16x8 bw[2][17];   // 136 VGPRs
  float bias_r[4];
  float cst[4];      // c-state: lo lanes rows 0..15 (at0), hi lanes 16..31 (at1)
#pragma unroll
  for (int r = 0; r < 4; ++r) cst[r] = 0.f;

  auto loadB = [&](const f16* WT, const float* bias) {
#pragma unroll
    for (int ct = 0; ct < 2; ++ct) {
      const f16* base = &WT[(size_t)(n0 + w * 32 + ct * 16 + l4) * K2 + q * 8];
#pragma unroll
      for (int ks = 0; ks < 17; ++ks) bw[ct][ks] = *(const f16x8*)(base + ks * 32);
    }
#pragma unroll
    for (int g = 0; g < 4; ++g)
      bias_r[g] = bias[n0 + w * 32 + (g >> 1) * 16 + (g & 1) * 8 + j];
  };

  loadB(encT, bE);
  float ow_r = 0.f;
  const int myUnit = u0 + w * 8 + j;
  const int fragBase = q * 256 + l4 * 8;  // lane offset within [ks][q][row32][8]

  for (int s = 0; s < SEQ + FCAST; ++s) {
    const bool enc = s < SEQ;
    if (s == SEQ) {
      loadB(decPW, bP);
      ow_r = outW[myUnit];
    } else if (s == SEQ + 1) {
      loadB(decFW, bF);
    }

    if (s > 0) {
      if (T == 0) {
        if (uni) {
          while (atomic_add_l2(myCnt, 0) < 16 * s) __builtin_amdgcn_s_sleep(1);
        } else {
          while (__hip_atomic_load(myCnt, __ATOMIC_RELAXED, __HIP_MEMORY_SCOPE_AGENT) < 16 * s)
            __builtin_amdgcn_s_sleep(2);
        }
      }
      __syncthreads();
    }

    const int pin = s & 1, pout = pin ^ 1;
    const f16* hbL = hbuf + (size_t)pin * HBP + (size_t)group * 16384 + fragBase;
    f16* hbO = hbuf + (size_t)pout * HBP + (size_t)group * 16384;

    // ---- GEMM: 8 batches of 2 ks x 2 at; fragments straight from L2 ----
    f32x4 acc[2][2];
#pragma unroll
    for (int a = 0; a < 2; ++a)
#pragma unroll
      for (int c = 0; c < 2; ++c) acc[a][c] = (f32x4){0.f, 0.f, 0.f, 0.f};

#pragma unroll
    for (int b = 0; b < 8; ++b) {
      f16x8 fr[2][2];
#pragma unroll
      for (int k2 = 0; k2 < 2; ++k2)
#pragma unroll
        for (int at = 0; at < 2; ++at)
          fr[k2][at] = ld16(&hbL[(b * 2 + k2) * 1024 + at * 128], !uni);
      wait_frags4(fr);
#pragma unroll
      for (int k2 = 0; k2 < 2; ++k2) {
        const int ks = b * 2 + k2;
#pragma unroll
        for (int at = 0; at < 2; ++at) {
          acc[at][0] =
              __builtin_amdgcn_mfma_f32_16x16x32_f16(fr[k2][at], bw[0][ks], acc[at][0], 0, 0, 0);
          acc[at][1] =
              __builtin_amdgcn_mfma_f32_16x16x32_f16(fr[k2][at], bw[1][ks], acc[at][1], 0, 0, 0);
        }
      }
    }

    if (enc) {  // ks=16: x chunk — q==0 lanes carry x (k 512..519)
#pragma unroll
      for (int at = 0; at < 2; ++at) {
        f16x8 af = {(f16)0.f, (f16)0.f, (f16)0.f, (f16)0.f,
                    (f16)0.f, (f16)0.f, (f16)0.f, (f16)0.f};
        if (q == 0) {
          const float* xp = &x[((size_t)(m0 + at * 16 + l4) * SEQ + s) * 8];
          float4 xa = *(const float4*)xp, xb = *(const float4*)(xp + 4);
          af = f16x8{(f16)xa.x, (f16)xa.y, (f16)xa.z, (f16)xa.w,
                     (f16)xb.x, (f16)xb.y, (f16)xb.z, (f16)xb.w};
        }
        acc[at][0] = __builtin_amdgcn_mfma_f32_16x16x32_f16(af, bw[0][16], acc[at][0], 0, 0, 0);
        acc[at][1] = __builtin_amdgcn_mfma_f32_16x16x32_f16(af, bw[1][16], acc[at][1], 0, 0, 0);
      }
    }

    // ---- pointwise: lane pair l4 <-> l4+8; lo lanes tile at0, hi tile at1 ----
#pragma unroll
    for (int r = 0; r < 4; ++r) {
      float xiL = acc[0][0][r], xgL = acc[0][1][r];
      float xiH = acc[1][0][r], xgH = acc[1][1][r];
      float payload0 = lo ? xiH : xiL;
      float payload1 = lo ? xgH : xgL;
      float recv0 = __shfl_xor(payload0, 8, 16);
      float recv1 = __shfl_xor(payload1, 8, 16);
      float pi = (lo ? xiL : recv0) + bias_r[0];
      float pf = (lo ? recv0 : xiH) + bias_r[1];
      float pg = (lo ? xgL : recv1) + bias_r[2];
      float po = (lo ? recv1 : xgH) + bias_r[3];
      float ig = sigf(pi), fg = sigf(pf), gg = tanhf_(pg), og = sigf(po);
      float cn = fg * cst[r] + ig * gg;
      cst[r] = cn;
      float hn = og * tanhf_(cn);
      int at = lo ? 0 : 1;
      int row = at * 16 + q * 4 + r;            // 0..31
      sH[row * SHS + w * 8 + j] = (f16)hn;
      if (!enc) {
        float pp = hn * ow_r;
        pp += __shfl_xor(pp, 1, 16);
        pp += __shfl_xor(pp, 2, 16);
        pp += __shfl_xor(pp, 4, 16);
        if (j == 0) atomicAdd(&out[(m0 + row) * FCAST + (s - SEQ)], pp);
      }
    }
    __syncthreads();

    // ---- store h octet (fragment layout, 2 KB): 128 threads x 16B + publish ----
    if (T < 128) {
      int row32 = T & 31, seg = T >> 5;  // seg = q slot 0..3
      f16x8 hv = *(const f16x8*)&sH[row32 * SHS + seg * 8];
      st16(&hbO[nslot * 1024 + seg * 256 + row32 * 8], hv, !uni);
    }
    asm volatile("s_waitcnt vmcnt(0)" ::: "memory");
    __syncthreads();
    if (T == 0) {
      if (uni) atomic_add_l2(myCnt, 1);
      else __hip_atomic_fetch_add(myCnt, 1, __ATOMIC_RELAXED, __HIP_MEMORY_SCOPE_AGENT);
    }
  }
}

extern "C" void kernel_launch(void* const* d_in, const int* in_sizes, int n_in, void* d_out,
                              int out_size, void* d_ws, size_t ws_size, hipStream_t stream) {
  const float* x = (const float*)d_in[0];
  const float* encWih = (const float*)d_in[1];
  const float* encWhh = (const float*)d_in[2];
  const float* encBih = (const float*)d_in[3];
  const float* encBhh = (const float*)d_in[4];
  const float* decWih = (const float*)d_in[5];
  const float* decWhh = (const float*)d_in[6];
  const float* decBih = (const float*)d_in[7];
  const float* decBhh = (const float*)d_in[8];
  const float* outW = (const float*)d_in[9];
  const float* outB = (const float*)d_in[10];
  float* out = (float*)d_out;

  char* ws = (char*)d_ws;
  f16* encT = (f16*)ws;                       // 3 x 2048*544*2 B = 6.7 MB
  f16* decPW = encT + 2048 * K2;
  f16* decFW = decPW + 2048 * K2;
  f16* hbuf = decFW + 2048 * K2;              // 2 MB
  float* bE = (float*)(hbuf + 2 * HBP);
  float* bP = bE + 2048;
  float* bF = bP + 2048;
  int* sync = (int*)(bF + 2048);              // 32 KB

  prep_weights<<<544, 256, 0, stream>>>(encWih, encWhh, decWih, decWhh, encBih, encBhh, decBih,
                                        decBhh, outW, outB, encT, decPW, decFW, bE, bP, bF);
  init_state<<<2048, 256, 0, stream>>>(hbuf, out, outB, sync);
  lstm_persist<<<512, 256, 0, stream>>>(encT, decPW, decFW, bE, bP, bF, x, outW, hbuf, out, sync);
}

// Round 14
// 2665.346 us; speedup vs baseline: 1.4182x; 1.4182x over previous
//
#include <hip/hip_runtime.h>

// LSTM encoder-decoder, MI355X. B=1024, S=256, IN=8, H=512, F=96.
// Persistent kernel, 256 wgs (1/CU). R14 = R9 with ONE change: the step
// barrier's poll is a LOAD, not an RMW. R9/R11/R12 kept ~7.7us/step because
// 16 T0s RMW-polling one L2 line serialize at the TCC (exclusive ownership
// per RMW) — arrivals queue behind the poll convoy. R13 (2 wgs/CU) showed TLP
// can't hide it (fabric traffic exploded, dur worsened). Fix: arrive =
// __hip_atomic_fetch_add(AGENT) at MALL; poll = __hip_atomic_load(AGENT)
// (concurrent loads, no ownership) — both intrinsics green in every round
// since R4 (self-org spin, mode-B). Ordering: h-stores are L2-acked
// (vmcnt(0)) BEFORE the MALL arrive is issued; consumers that see the counter
// read the same L2 that already holds the data. Banned asm poll_l2 not used.
// Data path = R9 verbatim: fragment-layout hbuf[parity][group][octet][row][8],
// single-ld16 ("=&v") sc0 loads, tied vmcnt(0) per 2-ks batch, weights in
// VGPRs (bw[2][17]=136), c-state in regs, decoder feedback folded into weights.
// Mode B (placement not 32/XCD): sc0 sc1 data path, same agent-scope sync.

#define Hh 512
#define K2 544
#define BATCH 1024
#define SEQ 256
#define FCAST 96
#define SHS 40                   // sH stride (f16)
#define HBP (16 * 64 * 64 * 8)   // hbuf f16 per parity

typedef _Float16 f16;
typedef _Float16 f16x8 __attribute__((ext_vector_type(8)));
typedef float f32x4 __attribute__((ext_vector_type(4)));

__device__ __forceinline__ float sigf(float v) { return 1.0f / (1.0f + __expf(-v)); }
__device__ __forceinline__ float tanhf_(float v) { return 1.0f - 2.0f / (__expf(2.0f * v) + 1.0f); }

__device__ __forceinline__ f16x8 ld16(const f16* p, bool byp) {
  f16x8 d;
  if (byp) asm volatile("global_load_dwordx4 %0, %1, off sc0 sc1" : "=&v"(d) : "v"(p) : "memory");
  else     asm volatile("global_load_dwordx4 %0, %1, off sc0"     : "=&v"(d) : "v"(p) : "memory");
  return d;
}
__device__ __forceinline__ void st16(f16* p, f16x8 v, bool byp) {
  if (byp) asm volatile("global_store_dwordx4 %0, %1, off sc0 sc1" :: "v"(p), "v"(v) : "memory");
  else     asm volatile("global_store_dwordx4 %0, %1, off"         :: "v"(p), "v"(v) : "memory");
}
__device__ __forceinline__ void wait_frags(f16x8 (&fr)[2][4]) {
  asm volatile("s_waitcnt vmcnt(0)"
               : "+v"(fr[0][0]), "+v"(fr[0][1]), "+v"(fr[0][2]), "+v"(fr[0][3]),
                 "+v"(fr[1][0]), "+v"(fr[1][1]), "+v"(fr[1][2]), "+v"(fr[1][3]));
}

// ---------------- prep: permute + fp16-convert + fold weights ----------------
// col n: nslot=n>>7, c=n&127, w=c>>5, cc=c&31, ct=cc>>4, l4=cc&15;
// gate=ct*2+(l4>>3), j=l4&7, unit=nslot*32+w*8+j; row r=gate*512+unit.
// K: [0,512)=Whh, [512,520)=Wih(enc), [520,544)=0.
__global__ void prep_weights(const float* __restrict__ encWih, const float* __restrict__ encWhh,
                             const float* __restrict__ decWih, const float* __restrict__ decWhh,
                             const float* __restrict__ encBih, const float* __restrict__ encBhh,
                             const float* __restrict__ decBih, const float* __restrict__ decBhh,
                             const float* __restrict__ outW, const float* __restrict__ outB,
                             f16* __restrict__ encT, f16* __restrict__ decPW, f16* __restrict__ decFW,
                             float* __restrict__ bE, float* __restrict__ bP, float* __restrict__ bF) {
  int id = blockIdx.x * 256 + threadIdx.x;
  if (id >= 2048 * 68) return;
  int n = id / 68, c8 = id % 68;
  int nslot = n >> 7, c = n & 127, w = c >> 5, cc = c & 31, ct = cc >> 4, l4v = cc & 15;
  int g = ct * 2 + (l4v >> 3), j = l4v & 7;
  int unit = nslot * 32 + w * 8 + j, r = g * Hh + unit;
  size_t o = (size_t)n * K2 + c8 * 8;
  if (c8 < 64) {
    float dwih = decWih[r];
#pragma unroll
    for (int e = 0; e < 8; ++e) {
      int k = c8 * 8 + e;
      encT[o + e] = (f16)encWhh[(size_t)r * Hh + k];
      float dw = decWhh[(size_t)r * Hh + k];
      decPW[o + e] = (f16)dw;
      decFW[o + e] = (f16)(dw + outW[k] * dwih);
    }
  } else if (c8 == 64) {
#pragma unroll
    for (int e = 0; e < 8; ++e) {
      encT[o + e] = (f16)encWih[r * 8 + e];
      decPW[o + e] = (f16)0.f;
      decFW[o + e] = (f16)0.f;
    }
  } else {
#pragma unroll
    for (int e = 0; e < 8; ++e) {
      encT[o + e] = (f16)0.f;
      decPW[o + e] = (f16)0.f;
      decFW[o + e] = (f16)0.f;
    }
  }
  if (c8 == 0) {
    bE[n] = encBih[r] + encBhh[r];
    float bd = decBih[r] + decBhh[r];
    bP[n] = bd;
    bF[n] = bd + outB[0] * decWih[r];
  }
}

__global__ void init_state(f16* __restrict__ hbuf, float* __restrict__ out,
                           const float* __restrict__ outB, int* __restrict__ sync) {
  int i = blockIdx.x * 256 + threadIdx.x;  // 2048 blocks -> 524288 threads
  unsigned int* hb = (unsigned int*)hbuf;  // 2*HBP f16 = 524288 u32
  if (i < 524288) hb[i] = 0u;
  if (i < BATCH * FCAST) out[i] = outB[0];
  if (i < 2048) sync[i] = 0;
}

// ---------------- persistent kernel ----------------
__global__ __launch_bounds__(256, 1) void lstm_persist(
    const f16* __restrict__ encT, const f16* __restrict__ decPW, const f16* __restrict__ decFW,
    const float* __restrict__ bE, const float* __restrict__ bP, const float* __restrict__ bF,
    const float* __restrict__ x, const float* __restrict__ outW,
    f16* __restrict__ hbuf, float* __restrict__ out, int* __restrict__ sync) {
  __shared__ __align__(16) f16 sH[64 * SHS];  // 5120 B
  __shared__ int sInfo[2];

  int* cnt = sync;            // 16 groups, stride 32 ints
  int* slots = sync + 1024;
  int* arrive = sync + 1032;

  const int T = threadIdx.x;
  const int w = T >> 6, lane = T & 63, l4 = lane & 15, q = lane >> 4;
  const int j = l4 & 7;
  const bool lo = (l4 < 8);

  int xcd;
  asm("s_getreg_b32 %0, hwreg(HW_REG_XCC_ID)" : "=s"(xcd));
  xcd &= 7;

  // ---- one-time self-organization (agent scope, proven) ----
  if (T == 0) {
    int r = __hip_atomic_fetch_add(&slots[xcd], 1, __ATOMIC_RELAXED, __HIP_MEMORY_SCOPE_AGENT);
    sInfo[0] = r;
    __hip_atomic_fetch_add(arrive, 1, __ATOMIC_RELAXED, __HIP_MEMORY_SCOPE_AGENT);
    while (__hip_atomic_load(arrive, __ATOMIC_RELAXED, __HIP_MEMORY_SCOPE_AGENT) < 256)
      __builtin_amdgcn_s_sleep(2);
    int ok = 1;
    for (int xx = 0; xx < 8; ++xx)
      ok &= (__hip_atomic_load(&slots[xx], __ATOMIC_RELAXED, __HIP_MEMORY_SCOPE_AGENT) == 32);
    sInfo[1] = ok;
  }
  __syncthreads();
  const int rank = sInfo[0];
  const bool uni = (sInfo[1] != 0);
  int group, nslot;
  if (uni) { group = xcd * 2 + (rank >> 4); nslot = rank & 15; }
  else     { group = (int)blockIdx.x >> 4;  nslot = (int)blockIdx.x & 15; }
  const int m0 = group * 64, n0 = nslot * 128, u0 = nslot * 32;
  int* myCnt = cnt + group * 32;

  f16x8 bw[2][17];   // 136 VGPRs
  float bias_r[4];
  float cst[2][4];
#pragma unroll
  for (int a = 0; a < 2; ++a)
#pragma unroll
    for (int r = 0; r < 4; ++r) cst[a][r] = 0.f;

  auto loadB = [&](const f16* WT, const float* bias) {
#pragma unroll
    for (int ct = 0; ct < 2; ++ct) {
      const f16* base = &WT[(size_t)(n0 + w * 32 + ct * 16 + l4) * K2 + q * 8];
#pragma unroll
      for (int ks = 0; ks < 17; ++ks) bw[ct][ks] = *(const f16x8*)(base + ks * 32);
    }
#pragma unroll
    for (int g = 0; g < 4; ++g)
      bias_r[g] = bias[n0 + w * 32 + (g >> 1) * 16 + (g & 1) * 8 + j];
  };

  loadB(encT, bE);
  float ow_r = 0.f;
  const int myUnit = u0 + w * 8 + j;
  const int fragBase = q * 512 + l4 * 8;  // lane offset within [octet][row][8]

  for (int s = 0; s < SEQ + FCAST; ++s) {
    const bool enc = s < SEQ;
    if (s == SEQ) {
      loadB(decPW, bP);
      ow_r = outW[myUnit];
    } else if (s == SEQ + 1) {
      loadB(decFW, bF);
    }

    if (s > 0) {
      // barrier wait: LOAD-poll at MALL (concurrent, convoy-free). Arrive was
      // issued at the end of step s-1 after h-stores were L2-acked.
      if (T == 0) {
        while (__hip_atomic_load(myCnt, __ATOMIC_RELAXED, __HIP_MEMORY_SCOPE_AGENT) < 16 * s)
          __builtin_amdgcn_s_sleep(1);
      }
      __syncthreads();
    }

    const int pin = s & 1, pout = pin ^ 1;
    const f16* hbL = hbuf + (size_t)pin * HBP + (size_t)group * 32768 + fragBase;
    f16* hbO = hbuf + (size_t)pout * HBP + (size_t)group * 32768;

    // ---- GEMM: A-fragments straight from L2 (mode A) / MALL (mode B) ----
    f32x4 acc[4][2];
#pragma unroll
    for (int a = 0; a < 4; ++a)
#pragma unroll
      for (int c = 0; c < 2; ++c) acc[a][c] = (f32x4){0.f, 0.f, 0.f, 0.f};

#pragma unroll
    for (int b = 0; b < 8; ++b) {
      f16x8 fr[2][4];
#pragma unroll
      for (int k2 = 0; k2 < 2; ++k2)
#pragma unroll
        for (int at = 0; at < 4; ++at)
          fr[k2][at] = ld16(&hbL[(b * 2 + k2) * 2048 + at * 128], !uni);
      wait_frags(fr);
#pragma unroll
      for (int k2 = 0; k2 < 2; ++k2) {
        const int ks = b * 2 + k2;
#pragma unroll
        for (int at = 0; at < 4; ++at) {
          acc[at][0] =
              __builtin_amdgcn_mfma_f32_16x16x32_f16(fr[k2][at], bw[0][ks], acc[at][0], 0, 0, 0);
          acc[at][1] =
              __builtin_amdgcn_mfma_f32_16x16x32_f16(fr[k2][at], bw[1][ks], acc[at][1], 0, 0, 0);
        }
      }
    }

    if (enc) {  // ks=16: x chunk — q==0 lanes carry x (k 512..519); rest zero-weighted
#pragma unroll
      for (int at = 0; at < 4; ++at) {
        f16x8 af = {(f16)0.f, (f16)0.f, (f16)0.f, (f16)0.f,
                    (f16)0.f, (f16)0.f, (f16)0.f, (f16)0.f};
        if (q == 0) {
          const float* xp = &x[((size_t)(m0 + at * 16 + l4) * SEQ + s) * 8];
          float4 xa = *(const float4*)xp, xb = *(const float4*)(xp + 4);
          af = f16x8{(f16)xa.x, (f16)xa.y, (f16)xa.z, (f16)xa.w,
                     (f16)xb.x, (f16)xb.y, (f16)xb.z, (f16)xb.w};
        }
        acc[at][0] = __builtin_amdgcn_mfma_f32_16x16x32_f16(af, bw[0][16], acc[at][0], 0, 0, 0);
        acc[at][1] = __builtin_amdgcn_mfma_f32_16x16x32_f16(af, bw[1][16], acc[at][1], 0, 0, 0);
      }
    }

    // ---- pointwise: lane pair l4 <-> l4+8 exchanges (i,g)<->(f,o) ----
#pragma unroll
    for (int ah = 0; ah < 2; ++ah) {
#pragma unroll
      for (int r = 0; r < 4; ++r) {
        int atL = ah, atH = ah + 2;
        float xiL = acc[atL][0][r], xgL = acc[atL][1][r];
        float xiH = acc[atH][0][r], xgH = acc[atH][1][r];
        float payload0 = lo ? xiH : xiL;
        float payload1 = lo ? xgH : xgL;
        float recv0 = __shfl_xor(payload0, 8, 16);
        float recv1 = __shfl_xor(payload1, 8, 16);
        float pi = (lo ? xiL : recv0) + bias_r[0];
        float pf = (lo ? recv0 : xiH) + bias_r[1];
        float pg = (lo ? xgL : recv1) + bias_r[2];
        float po = (lo ? recv1 : xgH) + bias_r[3];
        float ig = sigf(pi), fg = sigf(pf), gg = tanhf_(pg), og = sigf(po);
        float cn = fg * cst[ah][r] + ig * gg;
        cst[ah][r] = cn;
        float hn = og * tanhf_(cn);
        int at = lo ? atL : atH;
        int row = at * 16 + q * 4 + r;
        sH[row * SHS + w * 8 + j] = (f16)hn;
        if (!enc) {
          float pp = hn * ow_r;
          pp += __shfl_xor(pp, 1, 16);
          pp += __shfl_xor(pp, 2, 16);
          pp += __shfl_xor(pp, 4, 16);
          if (j == 0) atomicAdd(&out[(m0 + row) * FCAST + (s - SEQ)], pp);
        }
      }
    }
    __syncthreads();

    // ---- store h (fragment layout), drain to L2, then arrive at MALL ----
    {
      int row = lane, seg = w;
      f16x8 hv = *(const f16x8*)&sH[row * SHS + seg * 8];
      st16(&hbO[((nslot * 4 + seg) * 64 + row) * 8], hv, !uni);
    }
    asm volatile("s_waitcnt vmcnt(0)" ::: "memory");  // stores acked by L2/MALL
    __syncthreads();                                  // all waves drained
    if (T == 0)
      __hip_atomic_fetch_add(myCnt, 1, __ATOMIC_RELAXED, __HIP_MEMORY_SCOPE_AGENT);
  }
}

extern "C" void kernel_launch(void* const* d_in, const int* in_sizes, int n_in, void* d_out,
                              int out_size, void* d_ws, size_t ws_size, hipStream_t stream) {
  const float* x = (const float*)d_in[0];
  const float* encWih = (const float*)d_in[1];
  const float* encWhh = (const float*)d_in[2];
  const float* encBih = (const float*)d_in[3];
  const float* encBhh = (const float*)d_in[4];
  const float* decWih = (const float*)d_in[5];
  const float* decWhh = (const float*)d_in[6];
  const float* decBih = (const float*)d_in[7];
  const float* decBhh = (const float*)d_in[8];
  const float* outW = (const float*)d_in[9];
  const float* outB = (const float*)d_in[10];
  float* out = (float*)d_out;

  char* ws = (char*)d_ws;
  f16* encT = (f16*)ws;                       // 3 x 2048*544*2 B = 6.7 MB
  f16* decPW = encT + 2048 * K2;
  f16* decFW = decPW + 2048 * K2;
  f16* hbuf = decFW + 2048 * K2;              // 2 MB
  float* bE = (float*)(hbuf + 2 * HBP);
  float* bP = bE + 2048;
  float* bF = bP + 2048;
  int* sync = (int*)(bF + 2048);              // 8 KB

  prep_weights<<<544, 256, 0, stream>>>(encWih, encWhh, decWih, decWhh, encBih, encBhh, decBih,
                                        decBhh, outW, outB, encT, decPW, decFW, bE, bP, bF);
  init_state<<<2048, 256, 0, stream>>>(hbuf, out, outB, sync);
  lstm_persist<<<256, 256, 0, stream>>>(encT, decPW, decFW, bE, bP, bF, x, outW, hbuf, out, sync);
}